// Round 4
// baseline (246.505 us; speedup 1.0000x reference)
//
#include <hip/hip_runtime.h>
#include <hip/hip_bf16.h>

#define N_NODES 16000
#define N_EDGES 256000

// ---- workspace layout (4-byte units) — total 1022724*4B = 4.09 MB ----
#define OFF_SD     0          // int2  256000  (src,dst) per CSR slot, sorted by dst
#define OFF_SIMB   512000     // (unused after full fusion; kept for layout stability)
#define OFF_CNT    768000     // int   16000   per-dst degree
#define OFF_START  784000     // int   16001   CSR row offsets
#define OFF_CUR    800001     // int   16000   fill cursors
#define OFF_WB     816004     // f16   36864   WZ-V weights, B-frag order (18432 dwords)
#define OFF_WBK    834436     // f16   24576   WZ-K weights, B-frag order (12288 dwords)
#define OFF_QT     846724     // f16   320000  q-tilde per node (20 f16/node; 160000 dwords)
#define OFF_Z      1006724    // float 16000   per-dst sum of exp(sim)

typedef _Float16 f16x2 __attribute__((ext_vector_type(2)));
typedef _Float16 f16x8v __attribute__((ext_vector_type(8)));
typedef float f32x4v __attribute__((ext_vector_type(4)));

__device__ __forceinline__ float fdot2f(f16x2 a, f16x2 b, float c) {
#if __has_builtin(__builtin_amdgcn_fdot2)
  return __builtin_amdgcn_fdot2(a, b, c, false);
#else
  return fmaf((float)a.x, (float)b.x, fmaf((float)a.y, (float)b.y, c));
#endif
}

__device__ __forceinline__ unsigned packh2(float a, float b) {
  union { unsigned u; f16x2 p; } v;
  v.p.x = (_Float16)a; v.p.y = (_Float16)b;
  return v.u;
}

// splat one 16-bit half of a dword across both halves (1 v_perm_b32)
__device__ __forceinline__ unsigned splat_half(unsigned x, unsigned sel) {
#if __has_builtin(__builtin_amdgcn_perm)
  return __builtin_amdgcn_perm(x, x, sel);
#else
  unsigned h = (sel == 0x03020302u) ? (x >> 16) : (x & 0xffffu);
  return h | (h << 16);
#endif
}

__device__ __forceinline__ void load_row40(const float* __restrict__ p, float* xr) {
  const float4* rp = reinterpret_cast<const float4*>(p);
#pragma unroll
  for (int q = 0; q < 10; ++q) {
    float4 f = rp[q];
    xr[4 * q + 0] = f.x; xr[4 * q + 1] = f.y; xr[4 * q + 2] = f.z; xr[4 * q + 3] = f.w;
  }
}

struct EdgeGeom { float vhx, vhy, vhz, y1x, y1y, y1z; };

// ================= CSR build =================
__global__ void k_hist(const int* __restrict__ edst, int* __restrict__ cnt) {
  int e = blockIdx.x * 256 + threadIdx.x;
  atomicAdd(&cnt[edst[e]], 1);
}

__global__ void __launch_bounds__(1024) k_scan(const int* __restrict__ cnt,
                                               int* __restrict__ start, int* __restrict__ cur) {
  __shared__ int part[1024];
  int t = threadIdx.x;
  int base = t * 16;
  int local[16];
  int sum = 0;
#pragma unroll
  for (int i = 0; i < 16; ++i) {
    int idx = base + i;
    int c = (idx < N_NODES) ? cnt[idx] : 0;
    local[i] = sum; sum += c;
  }
  part[t] = sum;
  __syncthreads();
  for (int off = 1; off < 1024; off <<= 1) {
    int v = (t >= off) ? part[t - off] : 0;
    __syncthreads();
    part[t] += v;
    __syncthreads();
  }
  int prev = (t == 0) ? 0 : part[t - 1];
#pragma unroll
  for (int i = 0; i < 16; ++i) {
    int idx = base + i;
    if (idx < N_NODES) { int st = prev + local[i]; start[idx] = st; cur[idx] = st; }
  }
  if (t == 0) start[N_NODES] = N_EDGES;
}

__global__ void k_fill(const int* __restrict__ esrc, const int* __restrict__ edst,
                       int* __restrict__ cur, int2* __restrict__ sd) {
  int e = blockIdx.x * 256 + threadIdx.x;
  int d = edst[e];
  int slot = atomicAdd(&cur[d], 1);
  sd[slot] = make_int2(esrc[e], d);
}

// ============ prepack WZ-V[768][48] into B-fragment order (r16-validated) ============
__global__ void k_prepB(const float* __restrict__ Wv2, unsigned short* __restrict__ WB) {
  int idx = blockIdx.x * 256 + threadIdx.x;   // 144*256 = 36864
  int j = idx & 7;
  int lane = (idx >> 3) & 63;
  int t3 = idx >> 9;
  int ct = t3 % 3, kk = t3 / 3;
  int q = lane >> 4, m = lane & 15;
  int row = 32 * kk + 8 * q + j;
  int col = 16 * ct + m;
  int t = row & 15;
  float v = 0.f;
  if (row < 256) {
    int i = row >> 4;
    if (col < 16)      v = Wv2[t * 576 + i * 16 + col];
    else if (col < 24) v = Wv2[t * 576 + 384 + i * 8 + (col - 16)];
  } else if (row < 384) {
    int i = (row - 256) >> 4;
    if (col < 16)      v = Wv2[t * 576 + 256 + i * 16 + col];
  } else {
    int part = (row - 384) >> 7;
    int i = ((row - 384) & 127) >> 4;
    int cb = 24 + 8 * part;
    if (col >= cb && col < cb + 8) v = Wv2[t * 576 + 512 + i * 8 + (col - cb)];
  }
  union { unsigned short u; _Float16 h; } cv;
  cv.h = (_Float16)(v * 0.051031036307982884f);
  WB[idx] = cv.u;
}

// ============ prepack WZ-K[768][24->32] into B-fragment order (r17-validated) ============
__global__ void k_prepBK(const float* __restrict__ Wk2, unsigned short* __restrict__ WBK) {
  int idx = blockIdx.x * 256 + threadIdx.x;   // 96*256 = 24576
  int j = idx & 7;
  int lane = (idx >> 3) & 63;
  int t2 = idx >> 9;
  int ct = t2 & 1, kk = t2 >> 1;
  int q = lane >> 4, m = lane & 15;
  int row = 32 * kk + 8 * q + j;
  int col = 16 * ct + m;
  int t = row & 15;
  float v = 0.f;
  if (col < 24) {
    if (row < 256) {
      int i = row >> 4;
      if (col < 8)       v = Wk2[t * 288 + i * 8 + col];
      else if (col < 12) v = Wk2[t * 288 + 192 + i * 4 + (col - 8)];
    } else if (row < 384) {
      int i = (row - 256) >> 4;
      if (col < 8)       v = Wk2[t * 288 + 128 + i * 8 + col];
    } else {
      int c = (row - 384) >> 7;
      int i = ((row - 384) & 127) >> 4;
      int cb = 12 + 4 * c;
      if (col >= cb && col < cb + 4) v = Wk2[t * 288 + 256 + i * 4 + (col - cb)];
    }
  }
  union { unsigned short u; _Float16 h; } cv;
  cv.h = (_Float16)(v * 0.051031036307982884f);
  WBK[idx] = cv.u;
}

// ============ per-node q-tilde (q contracted with Wss/Wvv), f16 store ============
__global__ void __launch_bounds__(128) k_nodeq(
    const float* __restrict__ x,
    const float* __restrict__ Wq_s, const float* __restrict__ Wq_v,
    const float* __restrict__ Wss, const float* __restrict__ Wvv,
    unsigned short* __restrict__ QT) {
  __shared__ float Ls[240];
  for (int i = threadIdx.x; i < 240; i += 128) {
    float v;
    if (i < 128)      v = Wq_s[i] * 0.25f;
    else if (i < 160) v = Wq_v[i - 128] * 0.3535533905932738f;
    else if (i < 224) v = Wss[i - 160] * 0.11180339887498948f;
    else              v = Wvv[i - 224] * 0.06454972243679028f;
    Ls[i] = v;
  }
  __syncthreads();
  int n = blockIdx.x * 128 + threadIdx.x;   // 125*128 = 16000 exact
  float xd[40];
  load_row40(x + 40 * n, xd);
  float qd[8], qvd[12];
#pragma unroll
  for (int o = 0; o < 8; ++o) qd[o] = 0.f;
#pragma unroll
  for (int i = 0; i < 16; ++i)
#pragma unroll
    for (int o = 0; o < 8; ++o) qd[o] = fmaf(xd[i], Ls[8 * i + o], qd[o]);
#pragma unroll
  for (int k = 0; k < 12; ++k) qvd[k] = 0.f;
#pragma unroll
  for (int i = 0; i < 8; ++i)
#pragma unroll
    for (int o = 0; o < 4; ++o)
#pragma unroll
      for (int c = 0; c < 3; ++c)
        qvd[3 * o + c] = fmaf(xd[16 + 3 * i + c], Ls[128 + 4 * i + o], qvd[3 * o + c]);
  float qf[20];
#pragma unroll
  for (int j = 0; j < 8; ++j) {
    float t = 0.f;
#pragma unroll
    for (int i = 0; i < 8; ++i) t = fmaf(qd[i], Ls[160 + 8 * i + j], t);
    qf[j] = t;
  }
#pragma unroll
  for (int o = 0; o < 4; ++o)
#pragma unroll
    for (int c = 0; c < 3; ++c) {
      float t = 0.f;
#pragma unroll
      for (int i = 0; i < 4; ++i) t = fmaf(qvd[3 * i + c], Ls[224 + 4 * i + o], t);
      qf[8 + 3 * o + c] = t;
    }
  uint2* qp = (uint2*)(QT + 20 * n);   // 40B/node, 8B-aligned
#pragma unroll
  for (int b = 0; b < 5; ++b) {
    uint2 st;
    st.x = packh2(qf[4 * b], qf[4 * b + 1]);
    st.y = packh2(qf[4 * b + 2], qf[4 * b + 3]);
    qp[b] = st;
  }
}

// ---- shared per-wave SM row (stride RSTR dwords, 16B-aligned): [0..7] HT (h, 16 f16)
//      [8..31] CF (48 coefs as 24 f16-pair dwords: dword kk = {coef 2kk, coef 2kk+1}) ----
#define RSTR 36

// build coef[48] = {xs(16), Bv(8), xv pairs per component(24)} matching WZ row order
__device__ __forceinline__ void build_coef(const float* xr, const float* Bv, float* coef) {
#pragma unroll
  for (int i = 0; i < 16; ++i) coef[i] = xr[i];
#pragma unroll
  for (int i = 0; i < 8; ++i) coef[16 + i] = Bv[i];
#pragma unroll
  for (int p = 0; p < 4; ++p)
#pragma unroll
    for (int c = 0; c < 3; ++c) {
      coef[24 + 8 * c + 2 * p]     = xr[16 + 6 * p + c];
      coef[24 + 8 * c + 2 * p + 1] = xr[16 + 6 * p + 3 + c];
    }
}

// ======= fused edge pass: sequential K phase then V phase off one prologue =======
// NOTE: no occupancy hints — r1/r2 showed waves_per_eu / launch_bounds minima make
// the allocator under-allocate VGPRs and spill (64/84 VGPR + 100s of MB scratch).
__global__ void __launch_bounds__(256) k_edge(
    const float* __restrict__ pos, const float* __restrict__ x,
    const float* __restrict__ Wk1, const float* __restrict__ Wv1,
    const unsigned short* __restrict__ WBK, const unsigned short* __restrict__ WB,
    const unsigned short* __restrict__ QT,
    const int2* __restrict__ sd, float* __restrict__ Z, float* __restrict__ out) {
  __shared__ __align__(16) unsigned LWK[256];
  __shared__ __align__(16) unsigned LWV[256];
  __shared__ __align__(16) unsigned SM[4][64 * RSTR];

  int wave = threadIdx.x >> 6, lane = threadIdx.x & 63;
  int q = lane >> 4, m = lane & 15;
  int q1 = q & 1;
  unsigned seld = (q >> 1) ? 0x03020302u : 0x01000100u;
  int slot = blockIdx.x * 256 + threadIdx.x;
  int2 e = sd[slot];              // issue before LW staging; latency hides under it
  int s = e.x, d = e.y;

  // early raw q~ load (f16 pairs; converted post-K-loop)
  uint2 qraw[5];
  {
    const uint2* qp = (const uint2*)(QT + 20 * d);
#pragma unroll
    for (int b = 0; b < 5; ++b) qraw[b] = qp[b];
  }

  {
    int i = threadIdx.x;
    int bp = i >> 4, t = i & 15;
    LWK[i] = packh2(Wk1[(2 * bp) * 16 + t] * 0.17677669529663687f,
                    Wk1[(2 * bp + 1) * 16 + t] * 0.17677669529663687f);
    LWV[i] = packh2(Wv1[(2 * bp) * 16 + t] * 0.17677669529663687f,
                    Wv1[(2 * bp + 1) * 16 + t] * 0.17677669529663687f);
  }
  __syncthreads();

  // segment structure (sorted by dst) — used by both Z reduction and V scatter
  bool same[6];
#pragma unroll
  for (int k = 0; k < 6; ++k) {
    int dd = __shfl_down(d, 1 << k, 64);
    same[k] = ((lane + (1 << k)) < 64) && (dd == d);
  }
  int dprev = __shfl_up(d, 1, 64);
  bool head = (lane == 0) || (dprev != d);

  // ---- geometry + radial (Chebyshev) once; both W1 contractions (r2-validated) ----
  union { uint4 u[2]; unsigned dd[8]; } hKp, hVp;
  EdgeGeom g;
  {
    float vx = pos[3 * d + 0] - pos[3 * s + 0];
    float vy = pos[3 * d + 1] - pos[3 * s + 1];
    float vz = pos[3 * d + 2] - pos[3 * s + 2];
    float dist = sqrtf(fmaf(vx, vx, fmaf(vy, vy, vz * vz)));
    float dsafe = fmaxf(dist, 1e-6f);
    float rinv = 1.0f / dsafe;
    g.vhx = vx * rinv; g.vhy = vy * rinv; g.vhz = vz * rinv;
    g.y1x = 1.7320508075688772f * g.vhx;
    g.y1y = 1.7320508075688772f * g.vhy;
    g.y1z = 1.7320508075688772f * g.vhz;
    float preK[16], preV[16];
#pragma unroll
    for (int t = 0; t < 16; ++t) { preK[t] = 0.f; preV[t] = 0.f; }
    float sx, cx;
    sincosf(1.2566370614359172f * dsafe, &sx, &cx);
    cx = fminf(1.f, fmaxf(-1.f, cx));
    float twoc = 2.f * cx;
    float sprev = 0.f, scur = sx;
    float rscale = (dist < 2.5f) ? (5.059644256269407f * rinv) : 0.f;
#pragma unroll
    for (int bp = 0; bp < 16; ++bp) {
      float r0 = rscale * scur;
      float sn = fmaf(twoc, scur, -sprev); sprev = scur; scur = sn;
      float r1 = rscale * scur;
      sn = fmaf(twoc, scur, -sprev); sprev = scur; scur = sn;
      union { unsigned u; f16x2 p; } rp; rp.p.x = (_Float16)r0; rp.p.y = (_Float16)r1;
      union { uint4 u[4]; f16x2 p[16]; } wk, wv;
      wk.u[0] = *(const uint4*)(LWK + bp * 16);
      wk.u[1] = *(const uint4*)(LWK + bp * 16 + 4);
      wk.u[2] = *(const uint4*)(LWK + bp * 16 + 8);
      wk.u[3] = *(const uint4*)(LWK + bp * 16 + 12);
      wv.u[0] = *(const uint4*)(LWV + bp * 16);
      wv.u[1] = *(const uint4*)(LWV + bp * 16 + 4);
      wv.u[2] = *(const uint4*)(LWV + bp * 16 + 8);
      wv.u[3] = *(const uint4*)(LWV + bp * 16 + 12);
#pragma unroll
      for (int t = 0; t < 16; ++t) {
        preK[t] = fdot2f(rp.p, wk.p[t], preK[t]);
        preV[t] = fdot2f(rp.p, wv.p[t], preV[t]);
      }
    }
#pragma unroll
    for (int tp = 0; tp < 8; ++tp) {
      float k0 = preK[2 * tp]     / (1.f + __expf(-preK[2 * tp]));
      float k1 = preK[2 * tp + 1] / (1.f + __expf(-preK[2 * tp + 1]));
      float v0 = preV[2 * tp]     / (1.f + __expf(-preV[2 * tp]));
      float v1 = preV[2 * tp + 1] / (1.f + __expf(-preV[2 * tp + 1]));
      hKp.dd[tp] = packh2(k0, k1);
      hVp.dd[tp] = packh2(v0, v1);
    }
  }

  float xr[40];
  load_row40(x + 40 * s, xr);
  float Bv[8];
#pragma unroll
  for (int i = 0; i < 8; ++i)
    Bv[i] = fmaf(xr[16 + 3 * i], g.vhx, fmaf(xr[17 + 3 * i], g.vhy, xr[18 + 3 * i] * g.vhz));
  float coef[48];
  build_coef(xr, Bv, coef);

  // packed coef dwords kept live across phase K (restaged for phase V)
  union { uint4 u[6]; unsigned dd[24]; } cfp;
#pragma unroll
  for (int bt = 0; bt < 6; ++bt) {
    cfp.dd[4 * bt + 0] = packh2(coef[8 * bt + 0], coef[8 * bt + 1]);
    cfp.dd[4 * bt + 1] = packh2(coef[8 * bt + 2], coef[8 * bt + 3]);
    cfp.dd[4 * bt + 2] = packh2(coef[8 * bt + 4], coef[8 * bt + 5]);
    cfp.dd[4 * bt + 3] = packh2(coef[8 * bt + 6], coef[8 * bt + 7]);
  }

  unsigned* row = &SM[wave][lane * RSTR];
  unsigned* wbase = &SM[wave][0];
  float* ctb = (float*)wbase;

  // ================= phase K =================
  *(uint4*)(row)     = hKp.u[0];
  *(uint4*)(row + 4) = hKp.u[1];
#pragma unroll
  for (int bt = 0; bt < 6; ++bt) *(uint4*)(row + 8 + 4 * bt) = cfp.u[bt];

  union { uint4 u; f16x2 p[4]; } hs[4];
#pragma unroll
  for (int rt = 0; rt < 4; ++rt)
    hs[rt].u = *(const uint4*)(wbase + (16 * rt + m) * RSTR + 4 * q1);

  const uint4* WBKq = (const uint4*)WBK;
  f32x4v accK[4][2];
#pragma unroll
  for (int rt = 0; rt < 4; ++rt)
#pragma unroll
    for (int ct = 0; ct < 2; ++ct) { f32x4v z = {0.f, 0.f, 0.f, 0.f}; accK[rt][ct] = z; }

#pragma unroll
  for (int bt = 0; bt < 6; ++bt) {
    union { uint4 u; unsigned d[4]; } cb[4];
#pragma unroll
    for (int rt = 0; rt < 4; ++rt)
      cb[rt].u = *(const uint4*)(wbase + (16 * rt + m) * RSTR + 8 + 4 * bt);
#pragma unroll
    for (int t = 0; t < 4; ++t) {
      int kk = 4 * bt + t;
      union { uint4 u; f16x2 p[4]; f16x8v v; } av[4];
#pragma unroll
      for (int rt = 0; rt < 4; ++rt) {
        union { unsigned d; f16x2 p; } sp;
        sp.d = splat_half(cb[rt].d[t], seld);
#pragma unroll
        for (int w = 0; w < 4; ++w) av[rt].p[w] = hs[rt].p[w] * sp.p;
      }
#pragma unroll
      for (int ct = 0; ct < 2; ++ct) {
        union { uint4 u; f16x8v v; } bf;
        bf.u = WBKq[(kk * 2 + ct) * 64 + lane];
#pragma unroll
        for (int rt = 0; rt < 4; ++rt)
          accK[rt][ct] = __builtin_amdgcn_mfma_f32_16x16x32_f16(av[rt].v, bf.v, accK[rt][ct], 0, 0, 0);
      }
    }
  }

  // K C->P via col-major LDS (clobbers staging; restaged below)
  float P[24];
#pragma unroll
  for (int rt = 0; rt < 4; ++rt)
#pragma unroll
    for (int r = 0; r < 4; ++r)
      ctb[m * 65 + 16 * rt + 4 * q + r] = accK[rt][0][r];
#pragma unroll
  for (int o = 0; o < 16; ++o) P[o] = ctb[o * 65 + lane];
#pragma unroll
  for (int rt = 0; rt < 4; ++rt)
#pragma unroll
    for (int r = 0; r < 4; ++r)
      ctb[m * 65 + 16 * rt + 4 * q + r] = accK[rt][1][r];
#pragma unroll
  for (int o = 0; o < 8; ++o) P[16 + o] = ctb[o * 65 + lane];

  float qf[20];
#pragma unroll
  for (int b = 0; b < 5; ++b) {
    union { unsigned d; f16x2 p; } a0, a1;
    a0.d = qraw[b].x; a1.d = qraw[b].y;
    qf[4 * b] = (float)a0.p.x; qf[4 * b + 1] = (float)a0.p.y;
    qf[4 * b + 2] = (float)a1.p.x; qf[4 * b + 3] = (float)a1.p.y;
  }

  float sim = 0.f;
#pragma unroll
  for (int j = 0; j < 8; ++j) sim = fmaf(qf[j], P[j], sim);
  float y1c[3] = {g.y1x, g.y1y, g.y1z};
#pragma unroll
  for (int o = 0; o < 4; ++o)
#pragma unroll
    for (int c = 0; c < 3; ++c)
      sim = fmaf(qf[8 + 3 * o + c], fmaf(y1c[c], P[8 + o], P[12 + 4 * c + o]), sim);
  float ev = __expf(sim);

  // per-dst denominator (deferred normalization; k_div divides out/Z)
  {
    float v = ev;
#pragma unroll
    for (int k = 0; k < 6; ++k) {
      float ov = __shfl_down(v, 1 << k, 64);
      v += same[k] ? ov : 0.f;
    }
    if (head) atomicAdd(&Z[d], v);
  }

  // ================= phase V (restage; per-wave region, in-order) =================
  *(uint4*)(row)     = hVp.u[0];
  *(uint4*)(row + 4) = hVp.u[1];
#pragma unroll
  for (int bt = 0; bt < 6; ++bt) *(uint4*)(row + 8 + 4 * bt) = cfp.u[bt];

#pragma unroll
  for (int rt = 0; rt < 4; ++rt)
    hs[rt].u = *(const uint4*)(wbase + (16 * rt + m) * RSTR + 4 * q1);

  const uint4* WBq = (const uint4*)WB;
  f32x4v accV[4][3];
#pragma unroll
  for (int rt = 0; rt < 4; ++rt)
#pragma unroll
    for (int ct = 0; ct < 3; ++ct) { f32x4v z = {0.f, 0.f, 0.f, 0.f}; accV[rt][ct] = z; }

#pragma unroll
  for (int bt = 0; bt < 6; ++bt) {
    union { uint4 u; unsigned d[4]; } cb[4];
#pragma unroll
    for (int rt = 0; rt < 4; ++rt)
      cb[rt].u = *(const uint4*)(wbase + (16 * rt + m) * RSTR + 8 + 4 * bt);
#pragma unroll
    for (int t = 0; t < 4; ++t) {
      int kk = 4 * bt + t;
      union { uint4 u; f16x2 p[4]; f16x8v v; } av[4];
#pragma unroll
      for (int rt = 0; rt < 4; ++rt) {
        union { unsigned d; f16x2 p; } sp;
        sp.d = splat_half(cb[rt].d[t], seld);
#pragma unroll
        for (int w = 0; w < 4; ++w) av[rt].p[w] = hs[rt].p[w] * sp.p;
      }
#pragma unroll
      for (int ct = 0; ct < 3; ++ct) {
        union { uint4 u; f16x8v v; } bf;
        bf.u = WBq[(kk * 3 + ct) * 64 + lane];
#pragma unroll
        for (int rt = 0; rt < 4; ++rt)
          accV[rt][ct] = __builtin_amdgcn_mfma_f32_16x16x32_f16(av[rt].v, bf.v, accV[rt][ct], 0, 0, 0);
      }
    }
  }

  float* op = out + 40 * d;

  // chunk 0: out_s cols 0..15, weight ev (unnormalized)
  {
#pragma unroll
    for (int rt = 0; rt < 4; ++rt)
#pragma unroll
      for (int r = 0; r < 4; ++r)
        ctb[m * 65 + 16 * rt + 4 * q + r] = accV[rt][0][r];
    float P0[16];
#pragma unroll
    for (int o = 0; o < 16; ++o) P0[o] = ctb[o * 65 + lane];
#pragma unroll
    for (int o = 0; o < 16; ++o) {
      float v = ev * P0[o];
#pragma unroll
      for (int k = 0; k < 6; ++k) {
        float ov = __shfl_down(v, 1 << k, 64);
        v += same[k] ? ov : 0.f;
      }
      if (head) atomicAdd(op + o, v);
    }
  }
  // chunks 1,2
  float P1[16], P2[16];
#pragma unroll
  for (int rt = 0; rt < 4; ++rt)
#pragma unroll
    for (int r = 0; r < 4; ++r)
      ctb[m * 65 + 16 * rt + 4 * q + r] = accV[rt][1][r];
#pragma unroll
  for (int o = 0; o < 16; ++o) P1[o] = ctb[o * 65 + lane];
#pragma unroll
  for (int rt = 0; rt < 4; ++rt)
#pragma unroll
    for (int r = 0; r < 4; ++r)
      ctb[m * 65 + 16 * rt + 4 * q + r] = accV[rt][2][r];
#pragma unroll
  for (int o = 0; o < 16; ++o) P2[o] = ctb[o * 65 + lane];
#pragma unroll
  for (int o = 0; o < 8; ++o) {
    float s1v = P1[o];
    float vc[3];
    vc[0] = ev * fmaf(g.y1x, s1v, P1[8 + o]);
    vc[1] = ev * fmaf(g.y1y, s1v, P2[o]);
    vc[2] = ev * fmaf(g.y1z, s1v, P2[8 + o]);
#pragma unroll
    for (int c = 0; c < 3; ++c) {
      float v = vc[c];
#pragma unroll
      for (int k = 0; k < 6; ++k) {
        float ov = __shfl_down(v, 1 << k, 64);
        v += same[k] ? ov : 0.f;
      }
      if (head) atomicAdd(op + 16 + 3 * o + c, v);
    }
  }
}

// ---- final normalization: out[n][:] /= Z[n] ----
__global__ void k_div(const float* __restrict__ Z, float* __restrict__ out) {
  int i = blockIdx.x * 256 + threadIdx.x;   // 2500*256 = 640000 exact
  float z = Z[i / 40];
  if (z != 0.f) out[i] /= z;
}

extern "C" void kernel_launch(void* const* d_in, const int* in_sizes, int n_in,
                              void* d_out, int out_size, void* d_ws, size_t ws_size,
                              hipStream_t stream) {
  (void)in_sizes; (void)n_in; (void)out_size; (void)ws_size;
  const float* pos  = (const float*)d_in[0];
  const float* x    = (const float*)d_in[1];
  const float* Wq_s = (const float*)d_in[2];
  const float* Wq_v = (const float*)d_in[3];
  const float* Wk1  = (const float*)d_in[4];
  const float* Wk2  = (const float*)d_in[5];
  const float* Wv1  = (const float*)d_in[6];
  const float* Wv2  = (const float*)d_in[7];
  const float* Wss  = (const float*)d_in[8];
  const float* Wvv  = (const float*)d_in[9];
  const int* esrc = (const int*)d_in[10];
  const int* edst = (const int*)d_in[11];
  int*   wsi  = (int*)d_ws;
  float* wsf  = (float*)d_ws;
  float* out  = (float*)d_out;

  int2*  sd    = (int2*)(wsi + OFF_SD);
  int*   cnt   = wsi + OFF_CNT;
  int*   start = wsi + OFF_START;
  int*   cur   = wsi + OFF_CUR;
  unsigned short* WB  = (unsigned short*)(wsf + OFF_WB);
  unsigned short* WBK = (unsigned short*)(wsf + OFF_WBK);
  unsigned short* QT  = (unsigned short*)(wsf + OFF_QT);
  float* Z    = wsf + OFF_Z;

  hipMemsetAsync(cnt, 0, (size_t)N_NODES * sizeof(int), stream);
  hipMemsetAsync(Z, 0, (size_t)N_NODES * sizeof(float), stream);
  hipMemsetAsync(out, 0, (size_t)(N_NODES * 40) * sizeof(float), stream);
  k_prepB<<<144, 256, 0, stream>>>(Wv2, WB);
  k_prepBK<<<96, 256, 0, stream>>>(Wk2, WBK);
  k_nodeq<<<125, 128, 0, stream>>>(x, Wq_s, Wq_v, Wss, Wvv, QT);
  k_hist<<<1000, 256, 0, stream>>>(edst, cnt);
  k_scan<<<1, 1024, 0, stream>>>(cnt, start, cur);
  k_fill<<<1000, 256, 0, stream>>>(esrc, edst, cur, sd);
  k_edge<<<1000, 256, 0, stream>>>(pos, x, Wk1, Wv1, WBK, WB, QT, sd, Z, out);
  k_div<<<2500, 256, 0, stream>>>(Z, out);
}

// Round 5
// 220.160 us; speedup vs baseline: 1.1197x; 1.1197x over previous
//
#include <hip/hip_runtime.h>
#include <hip/hip_bf16.h>

#define N_NODES 16000
#define N_EDGES 256000

// ---- workspace layout (4-byte units) — total 1022724*4B = 4.09 MB ----
#define OFF_SD     0          // int2  256000  (src,dst) per CSR slot, sorted by dst
#define OFF_SIMB   512000     // float 256000  exp(sim) per slot
#define OFF_CNT    768000     // int   16000   per-dst degree
#define OFF_START  784000     // int   16001   CSR row offsets
#define OFF_CUR    800001     // int   16000   fill cursors
#define OFF_WB     816004     // f16   36864   WZ-V weights, B-frag order (18432 dwords)
#define OFF_WBK    834436     // f16   24576   WZ-K weights, B-frag order (12288 dwords)
#define OFF_QT     846724     // f16   320000  q-tilde per node (20 f16/node; 160000 dwords)
#define OFF_Z      1006724    // float 16000   per-dst sum of exp(sim)

typedef _Float16 f16x2 __attribute__((ext_vector_type(2)));
typedef _Float16 f16x8v __attribute__((ext_vector_type(8)));
typedef float f32x4v __attribute__((ext_vector_type(4)));

__device__ __forceinline__ float fdot2f(f16x2 a, f16x2 b, float c) {
#if __has_builtin(__builtin_amdgcn_fdot2)
  return __builtin_amdgcn_fdot2(a, b, c, false);
#else
  return fmaf((float)a.x, (float)b.x, fmaf((float)a.y, (float)b.y, c));
#endif
}

__device__ __forceinline__ unsigned packh2(float a, float b) {
  union { unsigned u; f16x2 p; } v;
  v.p.x = (_Float16)a; v.p.y = (_Float16)b;
  return v.u;
}

// splat one 16-bit half of a dword across both halves (1 v_perm_b32)
__device__ __forceinline__ unsigned splat_half(unsigned x, unsigned sel) {
#if __has_builtin(__builtin_amdgcn_perm)
  return __builtin_amdgcn_perm(x, x, sel);
#else
  unsigned h = (sel == 0x03020302u) ? (x >> 16) : (x & 0xffffu);
  return h | (h << 16);
#endif
}

__device__ __forceinline__ void load_row40(const float* __restrict__ p, float* xr) {
  const float4* rp = reinterpret_cast<const float4*>(p);
#pragma unroll
  for (int q = 0; q < 10; ++q) {
    float4 f = rp[q];
    xr[4 * q + 0] = f.x; xr[4 * q + 1] = f.y; xr[4 * q + 2] = f.z; xr[4 * q + 3] = f.w;
  }
}

struct EdgeGeom { float vhx, vhy, vhz, y1x, y1y, y1z; };

// geometry + radial basis + h = silu(rad @ W1n), packed as 8 f16 pairs (r11-validated)
__device__ __forceinline__ void edge_h_pk(const float* __restrict__ pos, int s, int d,
                                          const unsigned* W1, f16x2* hp, EdgeGeom& g) {
  float vx = pos[3 * d + 0] - pos[3 * s + 0];
  float vy = pos[3 * d + 1] - pos[3 * s + 1];
  float vz = pos[3 * d + 2] - pos[3 * s + 2];
  float dist = sqrtf(fmaf(vx, vx, fmaf(vy, vy, vz * vz)));
  float dsafe = fmaxf(dist, 1e-6f);
  float rinv = 1.0f / dsafe;
  g.vhx = vx * rinv; g.vhy = vy * rinv; g.vhz = vz * rinv;
  g.y1x = 1.7320508075688772f * g.vhx;
  g.y1y = 1.7320508075688772f * g.vhy;
  g.y1z = 1.7320508075688772f * g.vhz;
  float pre[16];
#pragma unroll
  for (int t = 0; t < 16; ++t) pre[t] = 0.f;
  float sx, cx;
  sincosf(1.2566370614359172f * dsafe, &sx, &cx);
  cx = fminf(1.f, fmaxf(-1.f, cx));
  float twoc = 2.f * cx;
  float sprev = 0.f, scur = sx;
  float rscale = (dist < 2.5f) ? (5.059644256269407f * rinv) : 0.f;
#pragma unroll
  for (int bp = 0; bp < 16; ++bp) {
    float r0 = rscale * scur;
    float sn = fmaf(twoc, scur, -sprev); sprev = scur; scur = sn;
    float r1 = rscale * scur;
    sn = fmaf(twoc, scur, -sprev); sprev = scur; scur = sn;
    union { unsigned u; f16x2 p; } rp; rp.p.x = (_Float16)r0; rp.p.y = (_Float16)r1;
    union { uint4 u[4]; f16x2 p[16]; } w;
    w.u[0] = *(const uint4*)(W1 + bp * 16);
    w.u[1] = *(const uint4*)(W1 + bp * 16 + 4);
    w.u[2] = *(const uint4*)(W1 + bp * 16 + 8);
    w.u[3] = *(const uint4*)(W1 + bp * 16 + 12);
#pragma unroll
    for (int t = 0; t < 16; ++t) pre[t] = fdot2f(rp.p, w.p[t], pre[t]);
  }
#pragma unroll
  for (int tp = 0; tp < 8; ++tp) {
    float h0 = pre[2 * tp]     / (1.f + __expf(-pre[2 * tp]));
    float h1 = pre[2 * tp + 1] / (1.f + __expf(-pre[2 * tp + 1]));
    hp[tp].x = (_Float16)h0; hp[tp].y = (_Float16)h1;
  }
}

// ================= CSR build =================
__global__ void k_hist(const int* __restrict__ edst, int* __restrict__ cnt) {
  int e = blockIdx.x * 256 + threadIdx.x;
  atomicAdd(&cnt[edst[e]], 1);
}

__global__ void __launch_bounds__(1024) k_scan(const int* __restrict__ cnt,
                                               int* __restrict__ start, int* __restrict__ cur) {
  __shared__ int part[1024];
  int t = threadIdx.x;
  int base = t * 16;
  int local[16];
  int sum = 0;
#pragma unroll
  for (int i = 0; i < 16; ++i) {
    int idx = base + i;
    int c = (idx < N_NODES) ? cnt[idx] : 0;
    local[i] = sum; sum += c;
  }
  part[t] = sum;
  __syncthreads();
  for (int off = 1; off < 1024; off <<= 1) {
    int v = (t >= off) ? part[t - off] : 0;
    __syncthreads();
    part[t] += v;
    __syncthreads();
  }
  int prev = (t == 0) ? 0 : part[t - 1];
#pragma unroll
  for (int i = 0; i < 16; ++i) {
    int idx = base + i;
    if (idx < N_NODES) { int st = prev + local[i]; start[idx] = st; cur[idx] = st; }
  }
  if (t == 0) start[N_NODES] = N_EDGES;
}

__global__ void k_fill(const int* __restrict__ esrc, const int* __restrict__ edst,
                       int* __restrict__ cur, int2* __restrict__ sd) {
  int e = blockIdx.x * 256 + threadIdx.x;
  int d = edst[e];
  int slot = atomicAdd(&cur[d], 1);
  sd[slot] = make_int2(esrc[e], d);
}

// ============ fused prep: zero(cnt,Z,out) + prepB + prepBK + nodeq ============
// block ranges: [0,2625) zero 672000 words; [2625,2769) prepB; [2769,2865) prepBK;
// [2865,2928) nodeq (n<16000 guard). Replaces 3 memsets + 3 kernels -> 1 dispatch.
#define PREP_ZERO_B   2625
#define PREP_PB_B     144
#define PREP_PBK_B    96
#define PREP_NQ_B     63
#define PREP_TOTAL_B  (PREP_ZERO_B + PREP_PB_B + PREP_PBK_B + PREP_NQ_B)

__global__ void __launch_bounds__(256) k_prep(
    const float* __restrict__ x,
    const float* __restrict__ Wq_s, const float* __restrict__ Wq_v,
    const float* __restrict__ Wss, const float* __restrict__ Wvv,
    const float* __restrict__ Wk2, const float* __restrict__ Wv2,
    int* __restrict__ cnt, float* __restrict__ Z, float* __restrict__ out,
    unsigned short* __restrict__ WB, unsigned short* __restrict__ WBK,
    unsigned short* __restrict__ QT) {
  int b = blockIdx.x;
  if (b < PREP_ZERO_B) {
    int i = b * 256 + threadIdx.x;          // 672000 exact
    if (i < 16000)       cnt[i] = 0;
    else if (i < 32000)  Z[i - 16000] = 0.f;
    else                 out[i - 32000] = 0.f;
    return;
  }
  b -= PREP_ZERO_B;
  if (b < PREP_PB_B) {
    int idx = b * 256 + threadIdx.x;        // 36864 exact
    int j = idx & 7;
    int lane = (idx >> 3) & 63;
    int t3 = idx >> 9;
    int ct = t3 % 3, kk = t3 / 3;
    int q = lane >> 4, m = lane & 15;
    int row = 32 * kk + 8 * q + j;
    int col = 16 * ct + m;
    int t = row & 15;
    float v = 0.f;
    if (row < 256) {
      int i = row >> 4;
      if (col < 16)      v = Wv2[t * 576 + i * 16 + col];
      else if (col < 24) v = Wv2[t * 576 + 384 + i * 8 + (col - 16)];
    } else if (row < 384) {
      int i = (row - 256) >> 4;
      if (col < 16)      v = Wv2[t * 576 + 256 + i * 16 + col];
    } else {
      int part = (row - 384) >> 7;
      int i = ((row - 384) & 127) >> 4;
      int cb = 24 + 8 * part;
      if (col >= cb && col < cb + 8) v = Wv2[t * 576 + 512 + i * 8 + (col - cb)];
    }
    union { unsigned short u; _Float16 h; } cv;
    cv.h = (_Float16)(v * 0.051031036307982884f);
    WB[idx] = cv.u;
    return;
  }
  b -= PREP_PB_B;
  if (b < PREP_PBK_B) {
    int idx = b * 256 + threadIdx.x;        // 24576 exact
    int j = idx & 7;
    int lane = (idx >> 3) & 63;
    int t2 = idx >> 9;
    int ct = t2 & 1, kk = t2 >> 1;
    int q = lane >> 4, m = lane & 15;
    int row = 32 * kk + 8 * q + j;
    int col = 16 * ct + m;
    int t = row & 15;
    float v = 0.f;
    if (col < 24) {
      if (row < 256) {
        int i = row >> 4;
        if (col < 8)       v = Wk2[t * 288 + i * 8 + col];
        else if (col < 12) v = Wk2[t * 288 + 192 + i * 4 + (col - 8)];
      } else if (row < 384) {
        int i = (row - 256) >> 4;
        if (col < 8)       v = Wk2[t * 288 + 128 + i * 8 + col];
      } else {
        int c = (row - 384) >> 7;
        int i = ((row - 384) & 127) >> 4;
        int cb = 12 + 4 * c;
        if (col >= cb && col < cb + 4) v = Wk2[t * 288 + 256 + i * 4 + (col - cb)];
      }
    }
    union { unsigned short u; _Float16 h; } cv;
    cv.h = (_Float16)(v * 0.051031036307982884f);
    WBK[idx] = cv.u;
    return;
  }
  b -= PREP_PBK_B;
  // ---- nodeq: per-node q-tilde, f16 store ----
  __shared__ float Ls[240];
  if (threadIdx.x < 240) {
    int i = threadIdx.x;
    float v;
    if (i < 128)      v = Wq_s[i] * 0.25f;
    else if (i < 160) v = Wq_v[i - 128] * 0.3535533905932738f;
    else if (i < 224) v = Wss[i - 160] * 0.11180339887498948f;
    else              v = Wvv[i - 224] * 0.06454972243679028f;
    Ls[i] = v;
  }
  __syncthreads();
  int n = b * 256 + threadIdx.x;
  if (n >= N_NODES) return;
  float xd[40];
  load_row40(x + 40 * n, xd);
  float qd[8], qvd[12];
#pragma unroll
  for (int o = 0; o < 8; ++o) qd[o] = 0.f;
#pragma unroll
  for (int i = 0; i < 16; ++i)
#pragma unroll
    for (int o = 0; o < 8; ++o) qd[o] = fmaf(xd[i], Ls[8 * i + o], qd[o]);
#pragma unroll
  for (int k = 0; k < 12; ++k) qvd[k] = 0.f;
#pragma unroll
  for (int i = 0; i < 8; ++i)
#pragma unroll
    for (int o = 0; o < 4; ++o)
#pragma unroll
      for (int c = 0; c < 3; ++c)
        qvd[3 * o + c] = fmaf(xd[16 + 3 * i + c], Ls[128 + 4 * i + o], qvd[3 * o + c]);
  float qf[20];
#pragma unroll
  for (int j = 0; j < 8; ++j) {
    float t = 0.f;
#pragma unroll
    for (int i = 0; i < 8; ++i) t = fmaf(qd[i], Ls[160 + 8 * i + j], t);
    qf[j] = t;
  }
#pragma unroll
  for (int o = 0; o < 4; ++o)
#pragma unroll
    for (int c = 0; c < 3; ++c) {
      float t = 0.f;
#pragma unroll
      for (int i = 0; i < 4; ++i) t = fmaf(qvd[3 * i + c], Ls[224 + 4 * i + o], t);
      qf[8 + 3 * o + c] = t;
    }
  uint2* qp = (uint2*)(QT + 20 * n);   // 40B/node, 8B-aligned
#pragma unroll
  for (int bq = 0; bq < 5; ++bq) {
    uint2 st;
    st.x = packh2(qf[4 * bq], qf[4 * bq + 1]);
    st.y = packh2(qf[4 * bq + 2], qf[4 * bq + 3]);
    qp[bq] = st;
  }
}

// ---- shared per-wave SM row (stride RSTR dwords, 16B-aligned): [0..7] HT (h, 16 f16)
//      [8..31] CF (48 coefs as 24 f16-pair dwords: dword kk = {coef 2kk, coef 2kk+1}) ----
#define RSTR 36

// build coef[48] = {xs(16), Bv(8), xv pairs per component(24)} matching WZ row order
__device__ __forceinline__ void build_coef(const float* xr, const float* Bv, float* coef) {
#pragma unroll
  for (int i = 0; i < 16; ++i) coef[i] = xr[i];
#pragma unroll
  for (int i = 0; i < 8; ++i) coef[16 + i] = Bv[i];
#pragma unroll
  for (int p = 0; p < 4; ++p)
#pragma unroll
    for (int c = 0; c < 3; ++c) {
      coef[24 + 8 * c + 2 * p]     = xr[16 + 6 * p + c];
      coef[24 + 8 * c + 2 * p + 1] = xr[16 + 6 * p + 3 + c];
    }
}

// ======= pass 1: Z-GEMM (CF-splat k-loop), one wave per block (LDS 10.2KB) =======
__global__ void __launch_bounds__(64) k_edge1(
    const float* __restrict__ pos, const float* __restrict__ x,
    const float* __restrict__ Wk1, const unsigned short* __restrict__ WBK,
    const unsigned short* __restrict__ QT,
    const int2* __restrict__ sd, float* __restrict__ simb, float* __restrict__ Z) {
  __shared__ __align__(16) unsigned LW1[256];
  __shared__ __align__(16) unsigned SM[64 * RSTR];

  for (int i = threadIdx.x; i < 256; i += 64) {
    int bp = i >> 4, t = i & 15;
    LW1[i] = packh2(Wk1[(2 * bp) * 16 + t] * 0.17677669529663687f,
                    Wk1[(2 * bp + 1) * 16 + t] * 0.17677669529663687f);
  }
  __syncthreads();

  int lane = threadIdx.x;
  int q = lane >> 4, m = lane & 15;
  int q1 = q & 1;
  unsigned seld = (q >> 1) ? 0x03020302u : 0x01000100u;
  int slot = blockIdx.x * 64 + threadIdx.x;
  int2 e = sd[slot];
  int s = e.x, d = e.y;

  f16x2 hp[8]; EdgeGeom g;
  edge_h_pk(pos, s, d, LW1, hp, g);

  // q~ load (f16, 20 halves)
  float qf[20];
  {
    const uint2* qp = (const uint2*)(QT + 20 * d);
#pragma unroll
    for (int b = 0; b < 5; ++b) {
      uint2 u = qp[b];
      union { unsigned d; f16x2 p; } a0, a1;
      a0.d = u.x; a1.d = u.y;
      qf[4 * b] = (float)a0.p.x; qf[4 * b + 1] = (float)a0.p.y;
      qf[4 * b + 2] = (float)a1.p.x; qf[4 * b + 3] = (float)a1.p.y;
    }
  }

  float xr[40];
  load_row40(x + 40 * s, xr);
  float Bv[8];
#pragma unroll
  for (int i = 0; i < 8; ++i)
    Bv[i] = fmaf(xr[16 + 3 * i], g.vhx, fmaf(xr[17 + 3 * i], g.vhy, xr[18 + 3 * i] * g.vhz));
  float coef[48];
  build_coef(xr, Bv, coef);

  unsigned* row = &SM[lane * RSTR];
  {
    union { uint4 u; f16x2 p[4]; } h0, h1;
#pragma unroll
    for (int k = 0; k < 4; ++k) { h0.p[k] = hp[k]; h1.p[k] = hp[4 + k]; }
    *(uint4*)(row) = h0.u;
    *(uint4*)(row + 4) = h1.u;
  }
#pragma unroll
  for (int bt = 0; bt < 6; ++bt) {
    uint4 w;
    w.x = packh2(coef[8 * bt + 0], coef[8 * bt + 1]);
    w.y = packh2(coef[8 * bt + 2], coef[8 * bt + 3]);
    w.z = packh2(coef[8 * bt + 4], coef[8 * bt + 5]);
    w.w = packh2(coef[8 * bt + 6], coef[8 * bt + 7]);
    *(uint4*)(row + 8 + 4 * bt) = w;
  }
  unsigned* wbase = &SM[0];
  union { uint4 u; f16x2 p[4]; } hs[4];
#pragma unroll
  for (int rt = 0; rt < 4; ++rt)
    hs[rt].u = *(const uint4*)(wbase + (16 * rt + m) * RSTR + 4 * q1);

  const uint4* WBq = (const uint4*)WBK;
  f32x4v acc[4][2];
#pragma unroll
  for (int rt = 0; rt < 4; ++rt)
#pragma unroll
    for (int ct = 0; ct < 2; ++ct) { f32x4v z = {0.f, 0.f, 0.f, 0.f}; acc[rt][ct] = z; }

#pragma unroll
  for (int bt = 0; bt < 6; ++bt) {
    union { uint4 u; unsigned d[4]; } cb[4];
#pragma unroll
    for (int rt = 0; rt < 4; ++rt)
      cb[rt].u = *(const uint4*)(wbase + (16 * rt + m) * RSTR + 8 + 4 * bt);
#pragma unroll
    for (int t = 0; t < 4; ++t) {
      int kk = 4 * bt + t;
      union { uint4 u; f16x2 p[4]; f16x8v v; } av[4];
#pragma unroll
      for (int rt = 0; rt < 4; ++rt) {
        union { unsigned d; f16x2 p; } sp;
        sp.d = splat_half(cb[rt].d[t], seld);
#pragma unroll
        for (int w = 0; w < 4; ++w) av[rt].p[w] = hs[rt].p[w] * sp.p;
      }
#pragma unroll
      for (int ct = 0; ct < 2; ++ct) {
        union { uint4 u; f16x8v v; } bf;
        bf.u = WBq[(kk * 2 + ct) * 64 + lane];
#pragma unroll
        for (int rt = 0; rt < 4; ++rt)
          acc[rt][ct] = __builtin_amdgcn_mfma_f32_16x16x32_f16(av[rt].v, bf.v, acc[rt][ct], 0, 0, 0);
      }
    }
  }

  // C -> P via col-major LDS (reuses wave region; single-wave in-order)
  float P[24];
  float* ctb = (float*)wbase;
#pragma unroll
  for (int rt = 0; rt < 4; ++rt)
#pragma unroll
    for (int r = 0; r < 4; ++r)
      ctb[m * 65 + 16 * rt + 4 * q + r] = acc[rt][0][r];
#pragma unroll
  for (int o = 0; o < 16; ++o) P[o] = ctb[o * 65 + lane];
#pragma unroll
  for (int rt = 0; rt < 4; ++rt)
#pragma unroll
    for (int r = 0; r < 4; ++r)
      ctb[m * 65 + 16 * rt + 4 * q + r] = acc[rt][1][r];
#pragma unroll
  for (int o = 0; o < 8; ++o) P[16 + o] = ctb[o * 65 + lane];

  float sim = 0.f;
#pragma unroll
  for (int j = 0; j < 8; ++j) sim = fmaf(qf[j], P[j], sim);
  float y1c[3] = {g.y1x, g.y1y, g.y1z};
#pragma unroll
  for (int o = 0; o < 4; ++o)
#pragma unroll
    for (int c = 0; c < 3; ++c)
      sim = fmaf(qf[8 + 3 * o + c], fmaf(y1c[c], P[8 + o], P[12 + 4 * c + o]), sim);

  // fused softmax numerator + per-dst denominator (reference uses plain exp, no max-shift)
  float ev = __expf(sim);
  simb[slot] = ev;
  bool same[6];
#pragma unroll
  for (int k = 0; k < 6; ++k) {
    int dd = __shfl_down(d, 1 << k, 64);
    same[k] = ((lane + (1 << k)) < 64) && (dd == d);
  }
  int dprev = __shfl_up(d, 1, 64);
  bool head = (lane == 0) || (dprev != d);
  float v = ev;
#pragma unroll
  for (int k = 0; k < 6; ++k) {
    float ov = __shfl_down(v, 1 << k, 64);
    v += same[k] ? ov : 0.f;
  }
  if (head) atomicAdd(&Z[d], v);
}

// ======= pass 2: Z-GEMM (CF-splat k-loop) + segmented scatter, one wave per block =======
__global__ void __launch_bounds__(64) k_edge2(
    const float* __restrict__ pos, const float* __restrict__ x,
    const float* __restrict__ Wv1, const unsigned short* __restrict__ WB,
    const int2* __restrict__ sd, const float* __restrict__ eb,
    const float* __restrict__ Zv, float* __restrict__ out) {
  __shared__ __align__(16) unsigned LW1[256];
  __shared__ __align__(16) unsigned SM[64 * RSTR];

  for (int i = threadIdx.x; i < 256; i += 64) {
    int bp = i >> 4, t = i & 15;
    LW1[i] = packh2(Wv1[(2 * bp) * 16 + t] * 0.17677669529663687f,
                    Wv1[(2 * bp + 1) * 16 + t] * 0.17677669529663687f);
  }
  __syncthreads();

  int lane = threadIdx.x;
  int q = lane >> 4, m = lane & 15;
  int q1 = q & 1;
  unsigned seld = (q >> 1) ? 0x03020302u : 0x01000100u;
  int slot = blockIdx.x * 64 + threadIdx.x;
  int2 e = sd[slot];
  int s = e.x, d = e.y;

  // attention weight: exp(sim) / Z[d]  (issue both loads early)
  float ev = eb[slot];
  float Zd = Zv[d];

  bool same[6];
#pragma unroll
  for (int k = 0; k < 6; ++k) {
    int dd = __shfl_down(d, 1 << k, 64);
    same[k] = ((lane + (1 << k)) < 64) && (dd == d);
  }
  int dprev = __shfl_up(d, 1, 64);
  bool head = (lane == 0) || (dprev != d);

  f16x2 hp[8]; EdgeGeom g;
  edge_h_pk(pos, s, d, LW1, hp, g);
  float xr[40];
  load_row40(x + 40 * s, xr);
  float Bv[8];
#pragma unroll
  for (int i = 0; i < 8; ++i)
    Bv[i] = fmaf(xr[16 + 3 * i], g.vhx, fmaf(xr[17 + 3 * i], g.vhy, xr[18 + 3 * i] * g.vhz));
  float coef[48];
  build_coef(xr, Bv, coef);
  float a = ev / Zd;

  unsigned* row = &SM[lane * RSTR];
  {
    union { uint4 u; f16x2 p[4]; } h0, h1;
#pragma unroll
    for (int k = 0; k < 4; ++k) { h0.p[k] = hp[k]; h1.p[k] = hp[4 + k]; }
    *(uint4*)(row) = h0.u;
    *(uint4*)(row + 4) = h1.u;
  }
#pragma unroll
  for (int bt = 0; bt < 6; ++bt) {
    uint4 w;
    w.x = packh2(coef[8 * bt + 0], coef[8 * bt + 1]);
    w.y = packh2(coef[8 * bt + 2], coef[8 * bt + 3]);
    w.z = packh2(coef[8 * bt + 4], coef[8 * bt + 5]);
    w.w = packh2(coef[8 * bt + 6], coef[8 * bt + 7]);
    *(uint4*)(row + 8 + 4 * bt) = w;
  }
  unsigned* wbase = &SM[0];
  union { uint4 u; f16x2 p[4]; } hs[4];
#pragma unroll
  for (int rt = 0; rt < 4; ++rt)
    hs[rt].u = *(const uint4*)(wbase + (16 * rt + m) * RSTR + 4 * q1);

  const uint4* WBq = (const uint4*)WB;
  f32x4v acc[4][3];
#pragma unroll
  for (int rt = 0; rt < 4; ++rt)
#pragma unroll
    for (int ct = 0; ct < 3; ++ct) { f32x4v z = {0.f, 0.f, 0.f, 0.f}; acc[rt][ct] = z; }

#pragma unroll
  for (int bt = 0; bt < 6; ++bt) {
    union { uint4 u; unsigned d[4]; } cb[4];
#pragma unroll
    for (int rt = 0; rt < 4; ++rt)
      cb[rt].u = *(const uint4*)(wbase + (16 * rt + m) * RSTR + 8 + 4 * bt);
#pragma unroll
    for (int t = 0; t < 4; ++t) {
      int kk = 4 * bt + t;
      union { uint4 u; f16x2 p[4]; f16x8v v; } av[4];
#pragma unroll
      for (int rt = 0; rt < 4; ++rt) {
        union { unsigned d; f16x2 p; } sp;
        sp.d = splat_half(cb[rt].d[t], seld);
#pragma unroll
        for (int w = 0; w < 4; ++w) av[rt].p[w] = hs[rt].p[w] * sp.p;
      }
#pragma unroll
      for (int ct = 0; ct < 3; ++ct) {
        union { uint4 u; f16x8v v; } bf;
        bf.u = WBq[(kk * 3 + ct) * 64 + lane];
#pragma unroll
        for (int rt = 0; rt < 4; ++rt)
          acc[rt][ct] = __builtin_amdgcn_mfma_f32_16x16x32_f16(av[rt].v, bf.v, acc[rt][ct], 0, 0, 0);
      }
    }
  }

  float* ctb = (float*)wbase;
  float* op = out + 40 * d;

  // chunk 0: out_s cols 0..15
  {
#pragma unroll
    for (int rt = 0; rt < 4; ++rt)
#pragma unroll
      for (int r = 0; r < 4; ++r)
        ctb[m * 65 + 16 * rt + 4 * q + r] = acc[rt][0][r];
    float P0[16];
#pragma unroll
    for (int o = 0; o < 16; ++o) P0[o] = ctb[o * 65 + lane];
#pragma unroll
    for (int o = 0; o < 16; ++o) {
      float v = a * P0[o];
#pragma unroll
      for (int k = 0; k < 6; ++k) {
        float ov = __shfl_down(v, 1 << k, 64);
        v += same[k] ? ov : 0.f;
      }
      if (head) atomicAdd(op + o, v);
    }
  }
  // chunks 1,2
  float P1[16], P2[16];
#pragma unroll
  for (int rt = 0; rt < 4; ++rt)
#pragma unroll
    for (int r = 0; r < 4; ++r)
      ctb[m * 65 + 16 * rt + 4 * q + r] = acc[rt][1][r];
#pragma unroll
  for (int o = 0; o < 16; ++o) P1[o] = ctb[o * 65 + lane];
#pragma unroll
  for (int rt = 0; rt < 4; ++rt)
#pragma unroll
    for (int r = 0; r < 4; ++r)
      ctb[m * 65 + 16 * rt + 4 * q + r] = acc[rt][2][r];
#pragma unroll
  for (int o = 0; o < 16; ++o) P2[o] = ctb[o * 65 + lane];
#pragma unroll
  for (int o = 0; o < 8; ++o) {
    float s1v = P1[o];
    float vc[3];
    vc[0] = a * fmaf(g.y1x, s1v, P1[8 + o]);
    vc[1] = a * fmaf(g.y1y, s1v, P2[o]);
    vc[2] = a * fmaf(g.y1z, s1v, P2[8 + o]);
#pragma unroll
    for (int c = 0; c < 3; ++c) {
      float v = vc[c];
#pragma unroll
      for (int k = 0; k < 6; ++k) {
        float ov = __shfl_down(v, 1 << k, 64);
        v += same[k] ? ov : 0.f;
      }
      if (head) atomicAdd(op + 16 + 3 * o + c, v);
    }
  }
}

extern "C" void kernel_launch(void* const* d_in, const int* in_sizes, int n_in,
                              void* d_out, int out_size, void* d_ws, size_t ws_size,
                              hipStream_t stream) {
  (void)in_sizes; (void)n_in; (void)out_size; (void)ws_size;
  const float* pos  = (const float*)d_in[0];
  const float* x    = (const float*)d_in[1];
  const float* Wq_s = (const float*)d_in[2];
  const float* Wq_v = (const float*)d_in[3];
  const float* Wk1  = (const float*)d_in[4];
  const float* Wk2  = (const float*)d_in[5];
  const float* Wv1  = (const float*)d_in[6];
  const float* Wv2  = (const float*)d_in[7];
  const float* Wss  = (const float*)d_in[8];
  const float* Wvv  = (const float*)d_in[9];
  const int* esrc = (const int*)d_in[10];
  const int* edst = (const int*)d_in[11];
  int*   wsi  = (int*)d_ws;
  float* wsf  = (float*)d_ws;
  float* out  = (float*)d_out;

  int2*  sd    = (int2*)(wsi + OFF_SD);
  float* simb  = wsf + OFF_SIMB;
  int*   cnt   = wsi + OFF_CNT;
  int*   start = wsi + OFF_START;
  int*   cur   = wsi + OFF_CUR;
  unsigned short* WB  = (unsigned short*)(wsf + OFF_WB);
  unsigned short* WBK = (unsigned short*)(wsf + OFF_WBK);
  unsigned short* QT  = (unsigned short*)(wsf + OFF_QT);
  float* Z    = wsf + OFF_Z;

  k_prep<<<PREP_TOTAL_B, 256, 0, stream>>>(x, Wq_s, Wq_v, Wss, Wvv, Wk2, Wv2,
                                           cnt, Z, out, WB, WBK, QT);
  k_hist<<<1000, 256, 0, stream>>>(edst, cnt);
  k_scan<<<1, 1024, 0, stream>>>(cnt, start, cur);
  k_fill<<<1000, 256, 0, stream>>>(esrc, edst, cur, sd);
  k_edge1<<<4000, 64, 0, stream>>>(pos, x, Wk1, WBK, QT, sd, simb, Z);
  k_edge2<<<4000, 64, 0, stream>>>(pos, x, Wv1, WB, sd, simb, Z, out);
}

// Round 6
// 201.893 us; speedup vs baseline: 1.2210x; 1.0905x over previous
//
#include <hip/hip_runtime.h>
#include <hip/hip_bf16.h>

#define N_NODES 16000
#define N_EDGES 256000

// ---- workspace layout (4-byte units) — total 1022725*4B = 4.09 MB ----
#define OFF_SD     0          // int2  256000  (src,dst) per CSR slot, grouped by dst
#define OFF_SIMB   512000     // float 256000  exp(sim) per slot
#define OFF_CNT    768000     // int   16000   per-dst degree
#define OFF_START  784000     // (unused; kept for layout stability)
#define OFF_CUR    800001     // int   16000   fill cursors
#define OFF_WB     816004     // f16   36864   WZ-V weights, B-frag order (18432 dwords)
#define OFF_WBK    834436     // f16   24576   WZ-K weights, B-frag order (12288 dwords)
#define OFF_QT     846724     // f16   320000  q-tilde per node (20 f16/node; 160000 dwords)
#define OFF_Z      1006724    // float 16000   per-dst sum of exp(sim)
#define OFF_GT     1022724    // int   1       global segment-base counter

typedef _Float16 f16x2 __attribute__((ext_vector_type(2)));
typedef _Float16 f16x8v __attribute__((ext_vector_type(8)));
typedef float f32x4v __attribute__((ext_vector_type(4)));

__device__ __forceinline__ float fdot2f(f16x2 a, f16x2 b, float c) {
#if __has_builtin(__builtin_amdgcn_fdot2)
  return __builtin_amdgcn_fdot2(a, b, c, false);
#else
  return fmaf((float)a.x, (float)b.x, fmaf((float)a.y, (float)b.y, c));
#endif
}

__device__ __forceinline__ unsigned packh2(float a, float b) {
  union { unsigned u; f16x2 p; } v;
  v.p.x = (_Float16)a; v.p.y = (_Float16)b;
  return v.u;
}

// splat one 16-bit half of a dword across both halves (1 v_perm_b32)
__device__ __forceinline__ unsigned splat_half(unsigned x, unsigned sel) {
#if __has_builtin(__builtin_amdgcn_perm)
  return __builtin_amdgcn_perm(x, x, sel);
#else
  unsigned h = (sel == 0x03020302u) ? (x >> 16) : (x & 0xffffu);
  return h | (h << 16);
#endif
}

// async 16B global->LDS DMA (linear dest = wave-uniform base + lane*16; m97 pattern)
__device__ __forceinline__ void gload_lds16(const unsigned* g, unsigned* l) {
#if __has_builtin(__builtin_amdgcn_global_load_lds)
  __builtin_amdgcn_global_load_lds((const __attribute__((address_space(1))) unsigned*)g,
                                   (__attribute__((address_space(3))) unsigned*)l, 16, 0, 0);
#else
  *(uint4*)l = *(const uint4*)g;
#endif
}

__device__ __forceinline__ void load_row40(const float* __restrict__ p, float* xr) {
  const float4* rp = reinterpret_cast<const float4*>(p);
#pragma unroll
  for (int q = 0; q < 10; ++q) {
    float4 f = rp[q];
    xr[4 * q + 0] = f.x; xr[4 * q + 1] = f.y; xr[4 * q + 2] = f.z; xr[4 * q + 3] = f.w;
  }
}

struct EdgeGeom { float vhx, vhy, vhz, y1x, y1y, y1z; };

// geometry + radial basis + h = silu(rad @ W1n), packed as 8 f16 pairs (r11-validated)
__device__ __forceinline__ void edge_h_pk(const float* __restrict__ pos, int s, int d,
                                          const unsigned* W1, f16x2* hp, EdgeGeom& g) {
  float vx = pos[3 * d + 0] - pos[3 * s + 0];
  float vy = pos[3 * d + 1] - pos[3 * s + 1];
  float vz = pos[3 * d + 2] - pos[3 * s + 2];
  float dist = sqrtf(fmaf(vx, vx, fmaf(vy, vy, vz * vz)));
  float dsafe = fmaxf(dist, 1e-6f);
  float rinv = 1.0f / dsafe;
  g.vhx = vx * rinv; g.vhy = vy * rinv; g.vhz = vz * rinv;
  g.y1x = 1.7320508075688772f * g.vhx;
  g.y1y = 1.7320508075688772f * g.vhy;
  g.y1z = 1.7320508075688772f * g.vhz;
  float pre[16];
#pragma unroll
  for (int t = 0; t < 16; ++t) pre[t] = 0.f;
  float sx, cx;
  sincosf(1.2566370614359172f * dsafe, &sx, &cx);
  cx = fminf(1.f, fmaxf(-1.f, cx));
  float twoc = 2.f * cx;
  float sprev = 0.f, scur = sx;
  float rscale = (dist < 2.5f) ? (5.059644256269407f * rinv) : 0.f;
#pragma unroll
  for (int bp = 0; bp < 16; ++bp) {
    float r0 = rscale * scur;
    float sn = fmaf(twoc, scur, -sprev); sprev = scur; scur = sn;
    float r1 = rscale * scur;
    sn = fmaf(twoc, scur, -sprev); sprev = scur; scur = sn;
    union { unsigned u; f16x2 p; } rp; rp.p.x = (_Float16)r0; rp.p.y = (_Float16)r1;
    union { uint4 u[4]; f16x2 p[16]; } w;
    w.u[0] = *(const uint4*)(W1 + bp * 16);
    w.u[1] = *(const uint4*)(W1 + bp * 16 + 4);
    w.u[2] = *(const uint4*)(W1 + bp * 16 + 8);
    w.u[3] = *(const uint4*)(W1 + bp * 16 + 12);
#pragma unroll
    for (int t = 0; t < 16; ++t) pre[t] = fdot2f(rp.p, w.p[t], pre[t]);
  }
#pragma unroll
  for (int tp = 0; tp < 8; ++tp) {
    float h0 = pre[2 * tp]     / (1.f + __expf(-pre[2 * tp]));
    float h1 = pre[2 * tp + 1] / (1.f + __expf(-pre[2 * tp + 1]));
    hp[tp].x = (_Float16)h0; hp[tp].y = (_Float16)h1;
  }
}

// ================= CSR build =================
__global__ void k_hist(const int* __restrict__ edst, int* __restrict__ cnt) {
  int e = blockIdx.x * 256 + threadIdx.x;
  atomicAdd(&cnt[edst[e]], 1);
}

// parallel segment-base assignment: order of segments is irrelevant (disjoint cover)
__global__ void k_scan2(const int* __restrict__ cnt, int* __restrict__ cur,
                        int* __restrict__ gtot) {
  int n = blockIdx.x * 256 + threadIdx.x;   // 63*256 = 16128, guard
  if (n < N_NODES) cur[n] = atomicAdd(gtot, cnt[n]);
}

__global__ void k_fill(const int* __restrict__ esrc, const int* __restrict__ edst,
                       int* __restrict__ cur, int2* __restrict__ sd) {
  int e = blockIdx.x * 256 + threadIdx.x;
  int d = edst[e];
  int slot = atomicAdd(&cur[d], 1);
  sd[slot] = make_int2(esrc[e], d);
}

// ============ fused prep: zero(cnt,Z,out,gtot) + prepB + prepBK + nodeq ============
#define PREP_ZERO_B   2626
#define PREP_PB_B     144
#define PREP_PBK_B    96
#define PREP_NQ_B     63
#define PREP_TOTAL_B  (PREP_ZERO_B + PREP_PB_B + PREP_PBK_B + PREP_NQ_B)

__global__ void __launch_bounds__(256) k_prep(
    const float* __restrict__ x,
    const float* __restrict__ Wq_s, const float* __restrict__ Wq_v,
    const float* __restrict__ Wss, const float* __restrict__ Wvv,
    const float* __restrict__ Wk2, const float* __restrict__ Wv2,
    int* __restrict__ cnt, float* __restrict__ Z, float* __restrict__ out,
    unsigned short* __restrict__ WB, unsigned short* __restrict__ WBK,
    unsigned short* __restrict__ QT, int* __restrict__ gtot) {
  int b = blockIdx.x;
  if (b < PREP_ZERO_B) {
    int i = b * 256 + threadIdx.x;
    if (i < 16000)       cnt[i] = 0;
    else if (i < 32000)  Z[i - 16000] = 0.f;
    else if (i < 672000) out[i - 32000] = 0.f;
    else if (i == 672000) *gtot = 0;
    return;
  }
  b -= PREP_ZERO_B;
  if (b < PREP_PB_B) {
    int idx = b * 256 + threadIdx.x;        // 36864 exact
    int j = idx & 7;
    int lane = (idx >> 3) & 63;
    int t3 = idx >> 9;
    int ct = t3 % 3, kk = t3 / 3;
    int q = lane >> 4, m = lane & 15;
    int row = 32 * kk + 8 * q + j;
    int col = 16 * ct + m;
    int t = row & 15;
    float v = 0.f;
    if (row < 256) {
      int i = row >> 4;
      if (col < 16)      v = Wv2[t * 576 + i * 16 + col];
      else if (col < 24) v = Wv2[t * 576 + 384 + i * 8 + (col - 16)];
    } else if (row < 384) {
      int i = (row - 256) >> 4;
      if (col < 16)      v = Wv2[t * 576 + 256 + i * 16 + col];
    } else {
      int part = (row - 384) >> 7;
      int i = ((row - 384) & 127) >> 4;
      int cb = 24 + 8 * part;
      if (col >= cb && col < cb + 8) v = Wv2[t * 576 + 512 + i * 8 + (col - cb)];
    }
    union { unsigned short u; _Float16 h; } cv;
    cv.h = (_Float16)(v * 0.051031036307982884f);
    WB[idx] = cv.u;
    return;
  }
  b -= PREP_PB_B;
  if (b < PREP_PBK_B) {
    int idx = b * 256 + threadIdx.x;        // 24576 exact
    int j = idx & 7;
    int lane = (idx >> 3) & 63;
    int t2 = idx >> 9;
    int ct = t2 & 1, kk = t2 >> 1;
    int q = lane >> 4, m = lane & 15;
    int row = 32 * kk + 8 * q + j;
    int col = 16 * ct + m;
    int t = row & 15;
    float v = 0.f;
    if (col < 24) {
      if (row < 256) {
        int i = row >> 4;
        if (col < 8)       v = Wk2[t * 288 + i * 8 + col];
        else if (col < 12) v = Wk2[t * 288 + 192 + i * 4 + (col - 8)];
      } else if (row < 384) {
        int i = (row - 256) >> 4;
        if (col < 8)       v = Wk2[t * 288 + 128 + i * 8 + col];
      } else {
        int c = (row - 384) >> 7;
        int i = ((row - 384) & 127) >> 4;
        int cb = 12 + 4 * c;
        if (col >= cb && col < cb + 4) v = Wk2[t * 288 + 256 + i * 4 + (col - cb)];
      }
    }
    union { unsigned short u; _Float16 h; } cv;
    cv.h = (_Float16)(v * 0.051031036307982884f);
    WBK[idx] = cv.u;
    return;
  }
  b -= PREP_PBK_B;
  // ---- nodeq: per-node q-tilde, f16 store ----
  __shared__ float Ls[240];
  if (threadIdx.x < 240) {
    int i = threadIdx.x;
    float v;
    if (i < 128)      v = Wq_s[i] * 0.25f;
    else if (i < 160) v = Wq_v[i - 128] * 0.3535533905932738f;
    else if (i < 224) v = Wss[i - 160] * 0.11180339887498948f;
    else              v = Wvv[i - 224] * 0.06454972243679028f;
    Ls[i] = v;
  }
  __syncthreads();
  int n = b * 256 + threadIdx.x;
  if (n >= N_NODES) return;
  float xd[40];
  load_row40(x + 40 * n, xd);
  float qd[8], qvd[12];
#pragma unroll
  for (int o = 0; o < 8; ++o) qd[o] = 0.f;
#pragma unroll
  for (int i = 0; i < 16; ++i)
#pragma unroll
    for (int o = 0; o < 8; ++o) qd[o] = fmaf(xd[i], Ls[8 * i + o], qd[o]);
#pragma unroll
  for (int k = 0; k < 12; ++k) qvd[k] = 0.f;
#pragma unroll
  for (int i = 0; i < 8; ++i)
#pragma unroll
    for (int o = 0; o < 4; ++o)
#pragma unroll
      for (int c = 0; c < 3; ++c)
        qvd[3 * o + c] = fmaf(xd[16 + 3 * i + c], Ls[128 + 4 * i + o], qvd[3 * o + c]);
  float qf[20];
#pragma unroll
  for (int j = 0; j < 8; ++j) {
    float t = 0.f;
#pragma unroll
    for (int i = 0; i < 8; ++i) t = fmaf(qd[i], Ls[160 + 8 * i + j], t);
    qf[j] = t;
  }
#pragma unroll
  for (int o = 0; o < 4; ++o)
#pragma unroll
    for (int c = 0; c < 3; ++c) {
      float t = 0.f;
#pragma unroll
      for (int i = 0; i < 4; ++i) t = fmaf(qvd[3 * i + c], Ls[224 + 4 * i + o], t);
      qf[8 + 3 * o + c] = t;
    }
  uint2* qp = (uint2*)(QT + 20 * n);   // 40B/node, 8B-aligned
#pragma unroll
  for (int bq = 0; bq < 5; ++bq) {
    uint2 st;
    st.x = packh2(qf[4 * bq], qf[4 * bq + 1]);
    st.y = packh2(qf[4 * bq + 2], qf[4 * bq + 3]);
    qp[bq] = st;
  }
}

// ---- shared per-wave SM row (stride RSTR dwords, 16B-aligned): [0..7] HT (h, 16 f16)
//      [8..31] CF (48 coefs as 24 f16-pair dwords: dword kk = {coef 2kk, coef 2kk+1}) ----
#define RSTR 36

// build coef[48] = {xs(16), Bv(8), xv pairs per component(24)} matching WZ row order
__device__ __forceinline__ void build_coef(const float* xr, const float* Bv, float* coef) {
#pragma unroll
  for (int i = 0; i < 16; ++i) coef[i] = xr[i];
#pragma unroll
  for (int i = 0; i < 8; ++i) coef[16 + i] = Bv[i];
#pragma unroll
  for (int p = 0; p < 4; ++p)
#pragma unroll
    for (int c = 0; c < 3; ++c) {
      coef[24 + 8 * c + 2 * p]     = xr[16 + 6 * p + c];
      coef[24 + 8 * c + 2 * p + 1] = xr[16 + 6 * p + 3 + c];
    }
}

// ======= pass 1: Z-GEMM; B staged through LDS double-buffer (8KB/bt, shared by 4 waves) =======
__global__ void __launch_bounds__(256) k_edge1(
    const float* __restrict__ pos, const float* __restrict__ x,
    const float* __restrict__ Wk1, const unsigned short* __restrict__ WBK,
    const unsigned short* __restrict__ QT,
    const int2* __restrict__ sd, float* __restrict__ simb, float* __restrict__ Z) {
  __shared__ __align__(16) unsigned LW1[256];
  __shared__ __align__(16) unsigned SM[4][64 * RSTR];
  __shared__ __align__(16) unsigned BB[2][2048];   // 2 × 8KB B-tiles

  {
    int i = threadIdx.x;
    int bp = i >> 4, t = i & 15;
    LW1[i] = packh2(Wk1[(2 * bp) * 16 + t] * 0.17677669529663687f,
                    Wk1[(2 * bp + 1) * 16 + t] * 0.17677669529663687f);
  }
  __syncthreads();

  int wave = threadIdx.x >> 6, lane = threadIdx.x & 63;
  int q = lane >> 4, m = lane & 15;
  int q1 = q & 1;
  unsigned seld = (q >> 1) ? 0x03020302u : 0x01000100u;
  int slot = blockIdx.x * 256 + threadIdx.x;
  int2 e = sd[slot];
  int s = e.x, d = e.y;

  f16x2 hp[8]; EdgeGeom g;
  edge_h_pk(pos, s, d, LW1, hp, g);

  // q~ load (f16, 20 halves)
  float qf[20];
  {
    const uint2* qp = (const uint2*)(QT + 20 * d);
#pragma unroll
    for (int b = 0; b < 5; ++b) {
      uint2 u = qp[b];
      union { unsigned d; f16x2 p; } a0, a1;
      a0.d = u.x; a1.d = u.y;
      qf[4 * b] = (float)a0.p.x; qf[4 * b + 1] = (float)a0.p.y;
      qf[4 * b + 2] = (float)a1.p.x; qf[4 * b + 3] = (float)a1.p.y;
    }
  }

  float xr[40];
  load_row40(x + 40 * s, xr);
  float Bv[8];
#pragma unroll
  for (int i = 0; i < 8; ++i)
    Bv[i] = fmaf(xr[16 + 3 * i], g.vhx, fmaf(xr[17 + 3 * i], g.vhy, xr[18 + 3 * i] * g.vhz));
  float coef[48];
  build_coef(xr, Bv, coef);

  unsigned* row = &SM[wave][lane * RSTR];
  {
    union { uint4 u; f16x2 p[4]; } h0, h1;
#pragma unroll
    for (int k = 0; k < 4; ++k) { h0.p[k] = hp[k]; h1.p[k] = hp[4 + k]; }
    *(uint4*)(row) = h0.u;
    *(uint4*)(row + 4) = h1.u;
  }
#pragma unroll
  for (int bt = 0; bt < 6; ++bt) {
    uint4 w;
    w.x = packh2(coef[8 * bt + 0], coef[8 * bt + 1]);
    w.y = packh2(coef[8 * bt + 2], coef[8 * bt + 3]);
    w.z = packh2(coef[8 * bt + 4], coef[8 * bt + 5]);
    w.w = packh2(coef[8 * bt + 6], coef[8 * bt + 7]);
    *(uint4*)(row + 8 + 4 * bt) = w;
  }
  unsigned* wbase = &SM[wave][0];
  union { uint4 u; f16x2 p[4]; } hs[4];
#pragma unroll
  for (int rt = 0; rt < 4; ++rt)
    hs[rt].u = *(const uint4*)(wbase + (16 * rt + m) * RSTR + 4 * q1);

  const uint4* WBq = (const uint4*)WBK;
  f32x4v acc[4][2];
#pragma unroll
  for (int rt = 0; rt < 4; ++rt)
#pragma unroll
    for (int ct = 0; ct < 2; ++ct) { f32x4v z = {0.f, 0.f, 0.f, 0.f}; acc[rt][ct] = z; }

  // prologue: stage bt=0 into buf 0 (512 uint4 per bt; 2 per thread)
#pragma unroll
  for (int j = 0; j < 2; ++j)
    gload_lds16((const unsigned*)(WBq + j * 256 + threadIdx.x),
                &BB[0][(j * 256 + threadIdx.x) * 4]);
  __syncthreads();

#pragma unroll
  for (int bt = 0; bt < 6; ++bt) {
    if (bt < 5) {
#pragma unroll
      for (int j = 0; j < 2; ++j)
        gload_lds16((const unsigned*)(WBq + (bt + 1) * 512 + j * 256 + threadIdx.x),
                    &BB[(bt + 1) & 1][(j * 256 + threadIdx.x) * 4]);
    }
    union { uint4 u; unsigned d[4]; } cb[4];
#pragma unroll
    for (int rt = 0; rt < 4; ++rt)
      cb[rt].u = *(const uint4*)(wbase + (16 * rt + m) * RSTR + 8 + 4 * bt);
    const uint4* Bq = (const uint4*)BB[bt & 1];
#pragma unroll
    for (int t = 0; t < 4; ++t) {
      union { uint4 u; f16x2 p[4]; f16x8v v; } av[4];
#pragma unroll
      for (int rt = 0; rt < 4; ++rt) {
        union { unsigned d; f16x2 p; } sp;
        sp.d = splat_half(cb[rt].d[t], seld);
#pragma unroll
        for (int w = 0; w < 4; ++w) av[rt].p[w] = hs[rt].p[w] * sp.p;
      }
#pragma unroll
      for (int ct = 0; ct < 2; ++ct) {
        union { uint4 u; f16x8v v; } bf;
        bf.u = Bq[(t * 2 + ct) * 64 + lane];
#pragma unroll
        for (int rt = 0; rt < 4; ++rt)
          acc[rt][ct] = __builtin_amdgcn_mfma_f32_16x16x32_f16(av[rt].v, bf.v, acc[rt][ct], 0, 0, 0);
      }
    }
    __syncthreads();   // drains prefetch DMA; all waves done with buf[bt&1]
  }

  // C -> P via col-major LDS (reuses wave region; per-wave in-order)
  float P[24];
  float* ctb = (float*)wbase;
#pragma unroll
  for (int rt = 0; rt < 4; ++rt)
#pragma unroll
    for (int r = 0; r < 4; ++r)
      ctb[m * 65 + 16 * rt + 4 * q + r] = acc[rt][0][r];
#pragma unroll
  for (int o = 0; o < 16; ++o) P[o] = ctb[o * 65 + lane];
#pragma unroll
  for (int rt = 0; rt < 4; ++rt)
#pragma unroll
    for (int r = 0; r < 4; ++r)
      ctb[m * 65 + 16 * rt + 4 * q + r] = acc[rt][1][r];
#pragma unroll
  for (int o = 0; o < 8; ++o) P[16 + o] = ctb[o * 65 + lane];

  float sim = 0.f;
#pragma unroll
  for (int j = 0; j < 8; ++j) sim = fmaf(qf[j], P[j], sim);
  float y1c[3] = {g.y1x, g.y1y, g.y1z};
#pragma unroll
  for (int o = 0; o < 4; ++o)
#pragma unroll
    for (int c = 0; c < 3; ++c)
      sim = fmaf(qf[8 + 3 * o + c], fmaf(y1c[c], P[8 + o], P[12 + 4 * c + o]), sim);

  // fused softmax numerator + per-dst denominator
  float ev = __expf(sim);
  simb[slot] = ev;
  bool same[6];
#pragma unroll
  for (int k = 0; k < 6; ++k) {
    int dd = __shfl_down(d, 1 << k, 64);
    same[k] = ((lane + (1 << k)) < 64) && (dd == d);
  }
  int dprev = __shfl_up(d, 1, 64);
  bool head = (lane == 0) || (dprev != d);
  float v = ev;
#pragma unroll
  for (int k = 0; k < 6; ++k) {
    float ov = __shfl_down(v, 1 << k, 64);
    v += same[k] ? ov : 0.f;
  }
  if (head) atomicAdd(&Z[d], v);
}

// ======= pass 2: Z-GEMM + scatter; B staged through LDS double-buffer (12KB/bt) =======
__global__ void __launch_bounds__(256) k_edge2(
    const float* __restrict__ pos, const float* __restrict__ x,
    const float* __restrict__ Wv1, const unsigned short* __restrict__ WB,
    const int2* __restrict__ sd, const float* __restrict__ eb,
    const float* __restrict__ Zv, float* __restrict__ out) {
  __shared__ __align__(16) unsigned LW1[256];
  __shared__ __align__(16) unsigned SM[4][64 * RSTR];
  __shared__ __align__(16) unsigned BB[2][3072];   // 2 × 12KB B-tiles

  {
    int i = threadIdx.x;
    int bp = i >> 4, t = i & 15;
    LW1[i] = packh2(Wv1[(2 * bp) * 16 + t] * 0.17677669529663687f,
                    Wv1[(2 * bp + 1) * 16 + t] * 0.17677669529663687f);
  }
  __syncthreads();

  int wave = threadIdx.x >> 6, lane = threadIdx.x & 63;
  int q = lane >> 4, m = lane & 15;
  int q1 = q & 1;
  unsigned seld = (q >> 1) ? 0x03020302u : 0x01000100u;
  int slot = blockIdx.x * 256 + threadIdx.x;
  int2 e = sd[slot];
  int s = e.x, d = e.y;

  // attention weight: exp(sim) / Z[d]  (issue both loads early)
  float ev = eb[slot];
  float Zd = Zv[d];

  bool same[6];
#pragma unroll
  for (int k = 0; k < 6; ++k) {
    int dd = __shfl_down(d, 1 << k, 64);
    same[k] = ((lane + (1 << k)) < 64) && (dd == d);
  }
  int dprev = __shfl_up(d, 1, 64);
  bool head = (lane == 0) || (dprev != d);

  f16x2 hp[8]; EdgeGeom g;
  edge_h_pk(pos, s, d, LW1, hp, g);
  float xr[40];
  load_row40(x + 40 * s, xr);
  float Bv[8];
#pragma unroll
  for (int i = 0; i < 8; ++i)
    Bv[i] = fmaf(xr[16 + 3 * i], g.vhx, fmaf(xr[17 + 3 * i], g.vhy, xr[18 + 3 * i] * g.vhz));
  float coef[48];
  build_coef(xr, Bv, coef);
  float a = ev / Zd;

  unsigned* row = &SM[wave][lane * RSTR];
  {
    union { uint4 u; f16x2 p[4]; } h0, h1;
#pragma unroll
    for (int k = 0; k < 4; ++k) { h0.p[k] = hp[k]; h1.p[k] = hp[4 + k]; }
    *(uint4*)(row) = h0.u;
    *(uint4*)(row + 4) = h1.u;
  }
#pragma unroll
  for (int bt = 0; bt < 6; ++bt) {
    uint4 w;
    w.x = packh2(coef[8 * bt + 0], coef[8 * bt + 1]);
    w.y = packh2(coef[8 * bt + 2], coef[8 * bt + 3]);
    w.z = packh2(coef[8 * bt + 4], coef[8 * bt + 5]);
    w.w = packh2(coef[8 * bt + 6], coef[8 * bt + 7]);
    *(uint4*)(row + 8 + 4 * bt) = w;
  }
  unsigned* wbase = &SM[wave][0];
  union { uint4 u; f16x2 p[4]; } hs[4];
#pragma unroll
  for (int rt = 0; rt < 4; ++rt)
    hs[rt].u = *(const uint4*)(wbase + (16 * rt + m) * RSTR + 4 * q1);

  const uint4* WBq = (const uint4*)WB;
  f32x4v acc[4][3];
#pragma unroll
  for (int rt = 0; rt < 4; ++rt)
#pragma unroll
    for (int ct = 0; ct < 3; ++ct) { f32x4v z = {0.f, 0.f, 0.f, 0.f}; acc[rt][ct] = z; }

  // prologue: stage bt=0 into buf 0 (768 uint4 per bt; 3 per thread)
#pragma unroll
  for (int j = 0; j < 3; ++j)
    gload_lds16((const unsigned*)(WBq + j * 256 + threadIdx.x),
                &BB[0][(j * 256 + threadIdx.x) * 4]);
  __syncthreads();

#pragma unroll
  for (int bt = 0; bt < 6; ++bt) {
    if (bt < 5) {
#pragma unroll
      for (int j = 0; j < 3; ++j)
        gload_lds16((const unsigned*)(WBq + (bt + 1) * 768 + j * 256 + threadIdx.x),
                    &BB[(bt + 1) & 1][(j * 256 + threadIdx.x) * 4]);
    }
    union { uint4 u; unsigned d[4]; } cb[4];
#pragma unroll
    for (int rt = 0; rt < 4; ++rt)
      cb[rt].u = *(const uint4*)(wbase + (16 * rt + m) * RSTR + 8 + 4 * bt);
    const uint4* Bq = (const uint4*)BB[bt & 1];
#pragma unroll
    for (int t = 0; t < 4; ++t) {
      union { uint4 u; f16x2 p[4]; f16x8v v; } av[4];
#pragma unroll
      for (int rt = 0; rt < 4; ++rt) {
        union { unsigned d; f16x2 p; } sp;
        sp.d = splat_half(cb[rt].d[t], seld);
#pragma unroll
        for (int w = 0; w < 4; ++w) av[rt].p[w] = hs[rt].p[w] * sp.p;
      }
#pragma unroll
      for (int ct = 0; ct < 3; ++ct) {
        union { uint4 u; f16x8v v; } bf;
        bf.u = Bq[(t * 3 + ct) * 64 + lane];
#pragma unroll
        for (int rt = 0; rt < 4; ++rt)
          acc[rt][ct] = __builtin_amdgcn_mfma_f32_16x16x32_f16(av[rt].v, bf.v, acc[rt][ct], 0, 0, 0);
      }
    }
    __syncthreads();   // drains prefetch DMA; all waves done with buf[bt&1]
  }

  float* ctb = (float*)wbase;
  float* op = out + 40 * d;

  // chunk 0: out_s cols 0..15
  {
#pragma unroll
    for (int rt = 0; rt < 4; ++rt)
#pragma unroll
      for (int r = 0; r < 4; ++r)
        ctb[m * 65 + 16 * rt + 4 * q + r] = acc[rt][0][r];
    float P0[16];
#pragma unroll
    for (int o = 0; o < 16; ++o) P0[o] = ctb[o * 65 + lane];
#pragma unroll
    for (int o = 0; o < 16; ++o) {
      float v = a * P0[o];
#pragma unroll
      for (int k = 0; k < 6; ++k) {
        float ov = __shfl_down(v, 1 << k, 64);
        v += same[k] ? ov : 0.f;
      }
      if (head) atomicAdd(op + o, v);
    }
  }
  // chunks 1,2
  float P1[16], P2[16];
#pragma unroll
  for (int rt = 0; rt < 4; ++rt)
#pragma unroll
    for (int r = 0; r < 4; ++r)
      ctb[m * 65 + 16 * rt + 4 * q + r] = acc[rt][1][r];
#pragma unroll
  for (int o = 0; o < 16; ++o) P1[o] = ctb[o * 65 + lane];
#pragma unroll
  for (int rt = 0; rt < 4; ++rt)
#pragma unroll
    for (int r = 0; r < 4; ++r)
      ctb[m * 65 + 16 * rt + 4 * q + r] = acc[rt][2][r];
#pragma unroll
  for (int o = 0; o < 16; ++o) P2[o] = ctb[o * 65 + lane];
#pragma unroll
  for (int o = 0; o < 8; ++o) {
    float s1v = P1[o];
    float vc[3];
    vc[0] = a * fmaf(g.y1x, s1v, P1[8 + o]);
    vc[1] = a * fmaf(g.y1y, s1v, P2[o]);
    vc[2] = a * fmaf(g.y1z, s1v, P2[8 + o]);
#pragma unroll
    for (int c = 0; c < 3; ++c) {
      float v = vc[c];
#pragma unroll
      for (int k = 0; k < 6; ++k) {
        float ov = __shfl_down(v, 1 << k, 64);
        v += same[k] ? ov : 0.f;
      }
      if (head) atomicAdd(op + 16 + 3 * o + c, v);
    }
  }
}

extern "C" void kernel_launch(void* const* d_in, const int* in_sizes, int n_in,
                              void* d_out, int out_size, void* d_ws, size_t ws_size,
                              hipStream_t stream) {
  (void)in_sizes; (void)n_in; (void)out_size; (void)ws_size;
  const float* pos  = (const float*)d_in[0];
  const float* x    = (const float*)d_in[1];
  const float* Wq_s = (const float*)d_in[2];
  const float* Wq_v = (const float*)d_in[3];
  const float* Wk1  = (const float*)d_in[4];
  const float* Wk2  = (const float*)d_in[5];
  const float* Wv1  = (const float*)d_in[6];
  const float* Wv2  = (const float*)d_in[7];
  const float* Wss  = (const float*)d_in[8];
  const float* Wvv  = (const float*)d_in[9];
  const int* esrc = (const int*)d_in[10];
  const int* edst = (const int*)d_in[11];
  int*   wsi  = (int*)d_ws;
  float* wsf  = (float*)d_ws;
  float* out  = (float*)d_out;

  int2*  sd    = (int2*)(wsi + OFF_SD);
  float* simb  = wsf + OFF_SIMB;
  int*   cnt   = wsi + OFF_CNT;
  int*   cur   = wsi + OFF_CUR;
  unsigned short* WB  = (unsigned short*)(wsf + OFF_WB);
  unsigned short* WBK = (unsigned short*)(wsf + OFF_WBK);
  unsigned short* QT  = (unsigned short*)(wsf + OFF_QT);
  float* Z    = wsf + OFF_Z;
  int*   gtot = wsi + OFF_GT;

  k_prep<<<PREP_TOTAL_B, 256, 0, stream>>>(x, Wq_s, Wq_v, Wss, Wvv, Wk2, Wv2,
                                           cnt, Z, out, WB, WBK, QT, gtot);
  k_hist<<<1000, 256, 0, stream>>>(edst, cnt);
  k_scan2<<<63, 256, 0, stream>>>(cnt, cur, gtot);
  k_fill<<<1000, 256, 0, stream>>>(esrc, edst, cur, sd);
  k_edge1<<<1000, 256, 0, stream>>>(pos, x, Wk1, WBK, QT, sd, simb, Z);
  k_edge2<<<1000, 256, 0, stream>>>(pos, x, Wv1, WB, sd, simb, Z, out);
}